// Round 13
// baseline (649.073 us; speedup 1.0000x reference)
//
#include <hip/hip_runtime.h>
#include <hip/hip_bf16.h>
#include <cstdint>

typedef __hip_bfloat16 bf16;
typedef __attribute__((ext_vector_type(8))) short frag8;   // 8 bf16 (4 VGPRs) MFMA operand
typedef __attribute__((ext_vector_type(4))) float f32x4;   // MFMA accumulator

#define DEV __device__ __forceinline__

DEV void gl_lds16(const void* g, void* l) {
  __builtin_amdgcn_global_load_lds(
      (const __attribute__((address_space(1))) void*)g,
      (__attribute__((address_space(3))) void*)l, 16, 0, 0);
}

DEV void storeC(float* C, size_t idx, float v) { C[idx] = v; }
DEV void storeC(bf16* C, size_t idx, float v) { C[idx] = __float2bfloat16(v); }

// ---------------- f32 -> bf16 conversion, all 5 tensors in one launch (R10-verified) ----------------
__global__ __launch_bounds__(256) void conv_all(const float* __restrict__ x,
                                                const float* __restrict__ wq,
                                                const float* __restrict__ wk,
                                                const float* __restrict__ wv,
                                                const float* __restrict__ wo,
                                                bf16* __restrict__ xb, bf16* __restrict__ qb,
                                                bf16* __restrict__ kb, bf16* __restrict__ vb,
                                                bf16* __restrict__ ob) {
  const float* src;
  bf16* dst;
  switch (blockIdx.y) {
    case 0: src = x;  dst = xb; break;
    case 1: src = wq; dst = qb; break;
    case 2: src = wk; dst = kb; break;
    case 3: src = wv; dst = vb; break;
    default: src = wo; dst = ob; break;
  }
  int i = blockIdx.x * 256 + threadIdx.x;
  const float4* in4 = reinterpret_cast<const float4*>(src);
  float4 a = in4[2 * i], b = in4[2 * i + 1];
  union { frag8 v; bf16 h[8]; } u;
  u.h[0] = __float2bfloat16(a.x); u.h[1] = __float2bfloat16(a.y);
  u.h[2] = __float2bfloat16(a.z); u.h[3] = __float2bfloat16(a.w);
  u.h[4] = __float2bfloat16(b.x); u.h[5] = __float2bfloat16(b.y);
  u.h[6] = __float2bfloat16(b.z); u.h[7] = __float2bfloat16(b.w);
  *reinterpret_cast<frag8*>(dst + (size_t)i * 8) = u.v;
}

// ---------------- GEMM (2-phase 256^2, BK=64, 8 waves, 16x16x32 MFMA): C = A * Bt^T ----------------
// EPI: 0 = plain store, 1 = fused RoPE (*oscale), 2 = V-transpose (C as vt[b][h][d][s]).
// 2 phases/K-tile (4 barriers, was 8): phase A = {8 B-frag + 4x2 A-frag reads, stage A(t+1),
// bar, 32 MFMA (mi 0-3), bar}; phase B = {4x2 A-frag reads, stage B(t+2), bar, 32 MFMA
// (mi 4-7), VM4, bar}. Staging/drain invariants identical to the R9-verified 4-phase form.
#define MF(a, b, c) __builtin_amdgcn_mfma_f32_16x16x32_bf16(a, b, c, 0, 0, 0)

#define STAGE(isB, h, tt, bp) do {                                             \
    char* _d = lds + ((isB) * 65536) + ((((bp) * 2) + (h)) << 14);             \
    gl_lds16(((isB) ? gB : gA)[h][0] + (size_t)(tt) * 64, _d + ldsOff0);       \
    gl_lds16(((isB) ? gB : gA)[h][1] + (size_t)(tt) * 64, _d + ldsOff1);       \
  } while (0)

#define RDA(mi, ckk) (*(const frag8*)(ab + aRowB + (mi) * 2048 + (ckk)))
#define RDB(ni, ckk) (*(const frag8*)(bb + bRowB + (ni) * 2048 + (ckk)))

// One 2-phase half-tile: computes mi = 4*ph .. 4*ph+3 over all 4 B columns, K=64.
#define PHASE2(ph, SSTAGE, SWPOST) do {                                        \
    if ((ph) == 0) {                                                           \
      b00 = RDB(0, ck0); b01 = RDB(0, ck1); b10 = RDB(1, ck0); b11 = RDB(1, ck1); \
      b20 = RDB(2, ck0); b21 = RDB(2, ck1); b30 = RDB(3, ck0); b31 = RDB(3, ck1); \
    }                                                                          \
    frag8 a00 = RDA(4 * (ph) + 0, ck0), a01 = RDA(4 * (ph) + 0, ck1);          \
    frag8 a10 = RDA(4 * (ph) + 1, ck0), a11 = RDA(4 * (ph) + 1, ck1);          \
    frag8 a20 = RDA(4 * (ph) + 2, ck0), a21 = RDA(4 * (ph) + 2, ck1);          \
    frag8 a30 = RDA(4 * (ph) + 3, ck0), a31 = RDA(4 * (ph) + 3, ck1);          \
    SSTAGE;                                                                    \
    __builtin_amdgcn_s_barrier();                                              \
    __builtin_amdgcn_s_setprio(1);                                             \
    acc[4*(ph)+0][0] = MF(a00, b00, acc[4*(ph)+0][0]);                         \
    acc[4*(ph)+0][1] = MF(a00, b10, acc[4*(ph)+0][1]);                         \
    acc[4*(ph)+0][2] = MF(a00, b20, acc[4*(ph)+0][2]);                         \
    acc[4*(ph)+0][3] = MF(a00, b30, acc[4*(ph)+0][3]);                         \
    acc[4*(ph)+1][0] = MF(a10, b00, acc[4*(ph)+1][0]);                         \
    acc[4*(ph)+1][1] = MF(a10, b10, acc[4*(ph)+1][1]);                         \
    acc[4*(ph)+1][2] = MF(a10, b20, acc[4*(ph)+1][2]);                         \
    acc[4*(ph)+1][3] = MF(a10, b30, acc[4*(ph)+1][3]);                         \
    acc[4*(ph)+2][0] = MF(a20, b00, acc[4*(ph)+2][0]);                         \
    acc[4*(ph)+2][1] = MF(a20, b10, acc[4*(ph)+2][1]);                         \
    acc[4*(ph)+2][2] = MF(a20, b20, acc[4*(ph)+2][2]);                         \
    acc[4*(ph)+2][3] = MF(a20, b30, acc[4*(ph)+2][3]);                         \
    acc[4*(ph)+3][0] = MF(a30, b00, acc[4*(ph)+3][0]);                         \
    acc[4*(ph)+3][1] = MF(a30, b10, acc[4*(ph)+3][1]);                         \
    acc[4*(ph)+3][2] = MF(a30, b20, acc[4*(ph)+3][2]);                         \
    acc[4*(ph)+3][3] = MF(a30, b30, acc[4*(ph)+3][3]);                         \
    acc[4*(ph)+0][0] = MF(a01, b01, acc[4*(ph)+0][0]);                         \
    acc[4*(ph)+0][1] = MF(a01, b11, acc[4*(ph)+0][1]);                         \
    acc[4*(ph)+0][2] = MF(a01, b21, acc[4*(ph)+0][2]);                         \
    acc[4*(ph)+0][3] = MF(a01, b31, acc[4*(ph)+0][3]);                         \
    acc[4*(ph)+1][0] = MF(a11, b01, acc[4*(ph)+1][0]);                         \
    acc[4*(ph)+1][1] = MF(a11, b11, acc[4*(ph)+1][1]);                         \
    acc[4*(ph)+1][2] = MF(a11, b21, acc[4*(ph)+1][2]);                         \
    acc[4*(ph)+1][3] = MF(a11, b31, acc[4*(ph)+1][3]);                         \
    acc[4*(ph)+2][0] = MF(a21, b01, acc[4*(ph)+2][0]);                         \
    acc[4*(ph)+2][1] = MF(a21, b11, acc[4*(ph)+2][1]);                         \
    acc[4*(ph)+2][2] = MF(a21, b21, acc[4*(ph)+2][2]);                         \
    acc[4*(ph)+2][3] = MF(a21, b31, acc[4*(ph)+2][3]);                         \
    acc[4*(ph)+3][0] = MF(a31, b01, acc[4*(ph)+3][0]);                         \
    acc[4*(ph)+3][1] = MF(a31, b11, acc[4*(ph)+3][1]);                         \
    acc[4*(ph)+3][2] = MF(a31, b21, acc[4*(ph)+3][2]);                         \
    acc[4*(ph)+3][3] = MF(a31, b31, acc[4*(ph)+3][3]);                         \
    __builtin_amdgcn_s_setprio(0);                                             \
    SWPOST;                                                                    \
    __builtin_amdgcn_s_barrier();                                              \
  } while (0)

#define VM4 asm volatile("s_waitcnt vmcnt(4)" ::: "memory")
#define VM0 asm volatile("s_waitcnt vmcnt(0)" ::: "memory")
#define NOW ((void)0)

#define TILE(t, SA, SB, SWPOST) do {                                           \
    const int _bp2 = ((t) & 1) * 2;                                            \
    char* ab = lds + ((_bp2 + wm) << 14);                                      \
    char* bb = lds + 65536 + ((_bp2 + bhalf) << 14);                           \
    PHASE2(0, { if (SA) { STAGE(0, 0, (t) + 1, ((t) + 1) & 1);                 \
                          STAGE(0, 1, (t) + 1, ((t) + 1) & 1); } }, NOW);      \
    PHASE2(1, { if (SB) { STAGE(1, 0, (t) + 2, (t) & 1);                       \
                          STAGE(1, 1, (t) + 2, (t) & 1); } }, SWPOST);         \
  } while (0)

template <typename OutT, int EPI>
__global__ __launch_bounds__(512, 2) void gemm8(const bf16* __restrict__ A,
                                                const bf16* __restrict__ Bt,
                                                OutT* __restrict__ C,
                                                const float* __restrict__ fc,
                                                const float* __restrict__ fs,
                                                float oscale) {
  __shared__ __align__(16) char lds[131072];
  const int K = 4096, N = 4096;
  const int t = threadIdx.x;
  const int lane = t & 63, w = t >> 6;
  const int wm = w >> 2, wn = w & 3;
  const int lr = lane & 15, lg = lane >> 4;
  const int bhalf = wn >> 1;

  const int bid = blockIdx.x;
  const int wg = (bid & 7) * 32 + (bid >> 3);
  const int m0 = (wg >> 4) * 256, n0 = (wg & 15) * 256;

  const bf16* gA[2][2];
  const bf16* gB[2][2];
  int ldsOff0, ldsOff1;
  {
    int c0 = (w * 2 + 0) * 64 + lane;
    int c1 = (w * 2 + 1) * 64 + lane;
    int r0 = c0 >> 3, r1 = c1 >> 3;
    int e0 = ((c0 & 7) ^ (r0 & 7)) * 8;
    int e1 = ((c1 & 7) ^ (r1 & 7)) * 8;
    ldsOff0 = c0 * 16; ldsOff1 = c1 * 16;
    gA[0][0] = A + (size_t)(m0 + r0) * K + e0;
    gA[0][1] = A + (size_t)(m0 + r1) * K + e1;
    gA[1][0] = A + (size_t)(m0 + 128 + r0) * K + e0;
    gA[1][1] = A + (size_t)(m0 + 128 + r1) * K + e1;
    gB[0][0] = Bt + (size_t)(n0 + r0) * K + e0;
    gB[0][1] = Bt + (size_t)(n0 + r1) * K + e1;
    gB[1][0] = Bt + (size_t)(n0 + 128 + r0) * K + e0;
    gB[1][1] = Bt + (size_t)(n0 + 128 + r1) * K + e1;
  }

  const int swz = (lr & 7) << 4;
  const int ck0 = (lg * 16) ^ swz;
  const int ck1 = (64 + lg * 16) ^ swz;
  const int aRowB = lr * 128;
  const int bRowB = ((wn & 1) * 64 + lr) * 128;

  f32x4 acc[8][4];
#pragma unroll
  for (int mi = 0; mi < 8; ++mi)
#pragma unroll
    for (int ni = 0; ni < 4; ++ni) acc[mi][ni] = (f32x4){0.f, 0.f, 0.f, 0.f};

  frag8 b00, b01, b10, b11, b20, b21, b30, b31;

  STAGE(1, 0, 0, 0); STAGE(1, 1, 0, 0);
  STAGE(0, 0, 0, 0); STAGE(0, 1, 0, 0);
  STAGE(1, 0, 1, 1); STAGE(1, 1, 1, 1);
  VM4;
  __builtin_amdgcn_s_barrier();

  for (int tt = 0; tt < 62; tt += 2) {
    TILE(tt, 1, 1, VM4);
    TILE(tt + 1, 1, 1, VM4);
  }
  TILE(62, 1, 0, VM0);
  TILE(63, 0, 0, NOW);

#pragma unroll
  for (int mi = 0; mi < 8; ++mi)
#pragma unroll
    for (int ni = 0; ni < 4; ++ni) {
      f32x4 v = acc[mi][ni];
      int col = n0 + wn * 64 + ni * 16 + lr;
      if (EPI == 1) {
        int i = (col & 127) >> 1;
        const bool odd = (col & 1);
#pragma unroll
        for (int ii = 0; ii < 4; ++ii) {
          int row = m0 + wm * 128 + mi * 16 + lg * 4 + ii;
          int s = row & 1023;
          float c = fc[s * 64 + i], si = fs[s * 64 + i];
          float val = v[ii];
          float par = __shfl_xor(val, 1);
          float o = (val * c + (odd ? par * si : -par * si)) * oscale;
          storeC(C, (size_t)row * N + col, o);
        }
      } else if (EPI == 2) {
        int row0 = m0 + wm * 128 + mi * 16 + lg * 4;
        size_t base = ((size_t)(row0 >> 10) * 4096 + col) * 1024 + (row0 & 1023);
        union { ushort4 s4; unsigned short us[4]; } pk;
#pragma unroll
        for (int ii = 0; ii < 4; ++ii) {
          union { bf16 b; unsigned short u; } cv;
          cv.b = __float2bfloat16(v[ii]);
          pk.us[ii] = cv.u;
        }
        *reinterpret_cast<ushort4*>(reinterpret_cast<bf16*>(C) + base) = pk.s4;
      } else {
#pragma unroll
        for (int ii = 0; ii < 4; ++ii) {
          int row = m0 + wm * 128 + mi * 16 + lg * 4 + ii;
          storeC(C, (size_t)row * N + col, v[ii]);
        }
      }
    }
}

// ---------------- Flash attention v8 (R8-verified, unchanged) ----------------
__global__ __launch_bounds__(512, 4) void attn_kernel(const bf16* __restrict__ q,
                                                      const bf16* __restrict__ k,
                                                      const bf16* __restrict__ vt,
                                                      bf16* __restrict__ out) {
  __shared__ __align__(16) char als[81920];
  const int qt = 7 - blockIdx.x, h = blockIdx.y, b = blockIdx.z;
  const int t = threadIdx.x;
  const int lane = t & 63, w = t >> 6;
  const int lr = lane & 15, lg = lane >> 4;
  const int NT = 2 * qt + 2;

  frag8 aq[4];  // Q pre-scaled by 1/sqrt(128) in the RoPE epilogue
  {
    const bf16* qp = q + ((size_t)(b * 1024 + qt * 128 + w * 16 + lr)) * 4096 + h * 128 + lg * 8;
#pragma unroll
    for (int ks = 0; ks < 4; ++ks) aq[ks] = *reinterpret_cast<const frag8*>(qp + ks * 32);
  }

  const bf16* kbase = k + (size_t)b * 1024 * 4096 + h * 128;
  const bf16* vbase = vt + ((size_t)(b * 32 + h)) * 128 * 1024;

  const int L0 = t * 16, L1 = (t + 512) * 16;
  const int kr0 = L0 >> 8, kr1 = L1 >> 8;
  const size_t kOff0 = (size_t)kr0 * 4096 + (((L0 & 255) ^ ((kr0 & 7) << 4)) >> 1);
  const size_t kOff1 = (size_t)kr1 * 4096 + (((L1 & 255) ^ ((kr1 & 7) << 4)) >> 1);
  const int vr0 = L0 >> 7, vr1 = L1 >> 7;
  const size_t vOff0 = (size_t)vr0 * 1024 + (((L0 & 127) ^ ((vr0 & 7) << 4)) >> 1);
  const size_t vOff1 = (size_t)vr1 * 1024 + (((L1 & 127) ^ ((vr1 & 7) << 4)) >> 1);

#define STAGE_K(tt, bp) do { char* _d = als + (bp) * 16384;                    \
    gl_lds16(kbase + (size_t)(tt) * 262144 + kOff0, _d + L0);                  \
    gl_lds16(kbase + (size_t)(tt) * 262144 + kOff1, _d + L1); } while (0)
#define STAGE_V(tt, bp) do { char* _d = als + 32768 + (bp) * 16384;            \
    gl_lds16(vbase + (size_t)(tt) * 64 + vOff0, _d + L0);                      \
    gl_lds16(vbase + (size_t)(tt) * 64 + vOff1, _d + L1); } while (0)

  f32x4 oacc[8] = {};
  float mrow = -1e30f, lrow = 0.f;
  char* Pw = als + 65536 + w * 2048;
  const int qmaxw = qt * 128 + w * 16 + 15;
  const int qr_g = qt * 128 + w * 16 + lr;

  STAGE_K(0, 0); STAGE_V(0, 0);
  STAGE_K(1, 1); STAGE_V(1, 1);

  for (int kt = 0; kt < NT; ++kt) {
    const int cur = kt & 1;
    const bool act = (kt * 64 <= qmaxw);
    const bool domask = (kt >= 2 * qt);
    char* Kc = als + cur * 16384;
    char* Vc = als + 32768 + cur * 16384;

    if (kt + 1 < NT) { VM4; } else { VM0; }
    __builtin_amdgcn_s_barrier();

    f32x4 sacc[4] = {};
    if (act) {
      __builtin_amdgcn_s_setprio(1);
#pragma unroll
      for (int ks = 0; ks < 4; ++ks) {
#pragma unroll
        for (int ni = 0; ni < 4; ++ni) {
          int n = ni * 16 + lr;
          frag8 bk = *reinterpret_cast<const frag8*>(
              Kc + n * 256 + ((ks * 64 + lg * 16) ^ ((n & 7) << 4)));
          sacc[ni] = MF(bk, aq[ks], sacc[ni]);   // SWAPPED: A=K, B=Q -> S^T
        }
      }
      __builtin_amdgcn_s_setprio(0);
    }
    __builtin_amdgcn_s_barrier();
    if (kt + 2 < NT) STAGE_K(kt + 2, cur);

    if (act) {
      if (domask) {
#pragma unroll
        for (int ni = 0; ni < 4; ++ni)
#pragma unroll
          for (int i = 0; i < 4; ++i) {
            int kc = kt * 64 + ni * 16 + lg * 4 + i;
            if (kc > qr_g) sacc[ni][i] = -1e30f;
          }
      }

      float pm = sacc[0][0];
#pragma unroll
      for (int ni = 0; ni < 4; ++ni)
#pragma unroll
        for (int i = 0; i < 4; ++i) pm = fmaxf(pm, sacc[ni][i]);
      pm = fmaxf(pm, __shfl_xor(pm, 16));
      pm = fmaxf(pm, __shfl_xor(pm, 32));
      const bool skip = __all(pm <= mrow + 8.f);
      float mn, f;
      if (skip) { mn = mrow; f = 1.f; }
      else      { mn = fmaxf(mrow, pm); f = __expf(mrow - mn); mrow = mn; }
      float rs = 0.f;
#pragma unroll
      for (int ni = 0; ni < 4; ++ni)
#pragma unroll
        for (int i = 0; i < 4; ++i) {
          float p = __expf(sacc[ni][i] - mn);
          sacc[ni][i] = p;
          rs += p;
        }
      rs += __shfl_xor(rs, 16);
      rs += __shfl_xor(rs, 32);
      lrow = lrow * f + rs;

#pragma unroll
      for (int ni = 0; ni < 4; ++ni)
#pragma unroll
        for (int jj = 0; jj < 2; ++jj) {
          union { uint32_t u; bf16 hh[2]; } pk;
          pk.hh[0] = __float2bfloat16(sacc[ni][2 * jj]);
          pk.hh[1] = __float2bfloat16(sacc[ni][2 * jj + 1]);
          int kc2 = (ni * 16 + lg * 4 + 2 * jj) * 2;
          *reinterpret_cast<uint32_t*>(Pw + lr * 128 + (kc2 ^ ((lr & 7) << 4))) = pk.u;
        }

      if (!skip) {
        float fi0 = __shfl(f, lg * 4 + 0);
        float fi1 = __shfl(f, lg * 4 + 1);
        float fi2 = __shfl(f, lg * 4 + 2);
        float fi3 = __shfl(f, lg * 4 + 3);
#pragma unroll
        for (int nj = 0; nj < 8; ++nj) {
          oacc[nj][0] *= fi0; oacc[nj][1] *= fi1;
          oacc[nj][2] *= fi2; oacc[nj][3] *= fi3;
        }
      }

      __builtin_amdgcn_s_setprio(1);
#pragma unroll
      for (int ks2 = 0; ks2 < 2; ++ks2) {
        frag8 ap = *reinterpret_cast<const frag8*>(
            Pw + lr * 128 + ((ks2 * 64 + lg * 16) ^ ((lr & 7) << 4)));
#pragma unroll
        for (int nj = 0; nj < 8; ++nj) {
          int d = nj * 16 + lr;
          frag8 bv = *reinterpret_cast<const frag8*>(
              Vc + d * 128 + ((ks2 * 64 + lg * 16) ^ ((d & 7) << 4)));
          oacc[nj] = MF(ap, bv, oacc[nj]);
        }
      }
      __builtin_amdgcn_s_setprio(0);
    }
    __builtin_amdgcn_s_barrier();
    if (kt + 2 < NT) STAGE_V(kt + 2, cur);
  }

  float lv0 = __shfl(lrow, lg * 4 + 0);
  float lv1 = __shfl(lrow, lg * 4 + 1);
  float lv2 = __shfl(lrow, lg * 4 + 2);
  float lv3 = __shfl(lrow, lg * 4 + 3);
#pragma unroll
  for (int nj = 0; nj < 8; ++nj) {
    int srow0 = qt * 128 + w * 16 + lg * 4;
    size_t base = ((size_t)(b * 1024 + srow0)) * 4096 + h * 128 + nj * 16 + lr;
    out[base]          = __float2bfloat16(oacc[nj][0] / lv0);
    out[base + 4096]   = __float2bfloat16(oacc[nj][1] / lv1);
    out[base + 8192]   = __float2bfloat16(oacc[nj][2] / lv2);
    out[base + 12288]  = __float2bfloat16(oacc[nj][3] / lv3);
  }
#undef STAGE_K
#undef STAGE_V
}

// ---------------- host launch ----------------
extern "C" void kernel_launch(void* const* d_in, const int* in_sizes, int n_in,
                              void* d_out, int out_size, void* d_ws, size_t ws_size,
                              hipStream_t stream) {
  const float* x  = (const float*)d_in[0];
  const float* fc = (const float*)d_in[2];
  const float* fs = (const float*)d_in[3];
  const float* wq = (const float*)d_in[5];
  const float* wk = (const float*)d_in[6];
  const float* wv = (const float*)d_in[7];
  const float* wo = (const float*)d_in[8];
  float* out = (float*)d_out;

  const size_t SZ = (size_t)4096 * 4096 * 2;
  char* w = (char*)d_ws;
  bf16* xb  = (bf16*)(w);
  bf16* wbq = (bf16*)(w + SZ);
  bf16* qb  = (bf16*)(w + 2 * SZ);
  bf16* kb  = (bf16*)(w + 3 * SZ);
  bf16* vtb = (bf16*)(w + 4 * SZ);  // V gemm writes transposed layout directly
  bf16* wbk = (bf16*)(w + 5 * SZ);
  bf16* wbv = (bf16*)(w + 6 * SZ);
  bf16* wbo = (bf16*)(w + 7 * SZ);
  bf16* ao  = xb;                    // xb dead after the three QKV GEMMs

  const int n8 = 4096 * 4096 / 8;
  dim3 cgrd(n8 / 256, 5), blk(256);
  dim3 ggrd(256);
  dim3 gblk(512);

  conv_all<<<cgrd, blk, 0, stream>>>(x, wq, wk, wv, wo, xb, wbq, wbk, wbv, wbo);
  gemm8<bf16, 1><<<ggrd, gblk, 0, stream>>>(xb, wbq, qb, fc, fs, 0.08838834764831845f);
  gemm8<bf16, 1><<<ggrd, gblk, 0, stream>>>(xb, wbk, kb, fc, fs, 1.0f);
  gemm8<bf16, 2><<<ggrd, gblk, 0, stream>>>(xb, wbv, vtb, fc, fs, 1.0f);
  attn_kernel<<<dim3(8, 32, 4), gblk, 0, stream>>>(qb, kb, vtb, ao);
  gemm8<float, 0><<<ggrd, gblk, 0, stream>>>(ao, wbo, out, fc, fs, 1.0f);
}

// Round 15
// 636.559 us; speedup vs baseline: 1.0197x; 1.0197x over previous
//
#include <hip/hip_runtime.h>
#include <hip/hip_bf16.h>
#include <cstdint>

typedef __hip_bfloat16 bf16;
typedef __attribute__((ext_vector_type(8))) short frag8;   // 8 bf16 (4 VGPRs) MFMA operand
typedef __attribute__((ext_vector_type(4))) float f32x4;   // MFMA accumulator / native f32x4

#define DEV __device__ __forceinline__

DEV void gl_lds16(const void* g, void* l) {
  __builtin_amdgcn_global_load_lds(
      (const __attribute__((address_space(1))) void*)g,
      (__attribute__((address_space(3))) void*)l, 16, 0, 0);
}

DEV void storeC(float* C, size_t idx, float v) { C[idx] = v; }
DEV void storeC(bf16* C, size_t idx, float v) { C[idx] = __float2bfloat16(v); }

// ---------------- f32 -> bf16 conversion, all 5 tensors, non-temporal ----------------
// Streaming data with zero reuse: bypass L2/L3 on both sides. Loads go through a native
// ext-vector type (the builtin rejects HIP_vector_type structs).
__global__ __launch_bounds__(256) void conv_all(const float* __restrict__ x,
                                                const float* __restrict__ wq,
                                                const float* __restrict__ wk,
                                                const float* __restrict__ wv,
                                                const float* __restrict__ wo,
                                                bf16* __restrict__ xb, bf16* __restrict__ qb,
                                                bf16* __restrict__ kb, bf16* __restrict__ vb,
                                                bf16* __restrict__ ob) {
  const float* src;
  bf16* dst;
  switch (blockIdx.y) {
    case 0: src = x;  dst = xb; break;
    case 1: src = wq; dst = qb; break;
    case 2: src = wk; dst = kb; break;
    case 3: src = wv; dst = vb; break;
    default: src = wo; dst = ob; break;
  }
  int i = blockIdx.x * 256 + threadIdx.x;
  const f32x4* in4 = reinterpret_cast<const f32x4*>(src);
  f32x4 a = __builtin_nontemporal_load(in4 + 2 * i);
  f32x4 b = __builtin_nontemporal_load(in4 + 2 * i + 1);
  union { frag8 v; bf16 h[8]; } u;
  u.h[0] = __float2bfloat16(a.x); u.h[1] = __float2bfloat16(a.y);
  u.h[2] = __float2bfloat16(a.z); u.h[3] = __float2bfloat16(a.w);
  u.h[4] = __float2bfloat16(b.x); u.h[5] = __float2bfloat16(b.y);
  u.h[6] = __float2bfloat16(b.z); u.h[7] = __float2bfloat16(b.w);
  __builtin_nontemporal_store(u.v, reinterpret_cast<frag8*>(dst + (size_t)i * 8));
}

// ---------------- GEMM (4-phase 256^2, BK=64, 8 waves, 16x16x32 MFMA): C = A * Bt^T ----------------
// EPI: 0 = plain store, 1 = fused RoPE (*oscale), 2 = V-transpose (C as vt[b][h][d][s]).
// R10-verified best: 122.5 us, 0 bank conflicts.
#define MF(a, b, c) __builtin_amdgcn_mfma_f32_16x16x32_bf16(a, b, c, 0, 0, 0)

#define STAGE(isB, h, tt, bp) do {                                             \
    char* _d = lds + ((isB) * 65536) + ((((bp) * 2) + (h)) << 14);             \
    gl_lds16(((isB) ? gB : gA)[h][0] + (size_t)(tt) * 64, _d + ldsOff0);       \
    gl_lds16(((isB) ? gB : gA)[h][1] + (size_t)(tt) * 64, _d + ldsOff1);       \
  } while (0)

#define RDA(mi, ckk) (*(const frag8*)(ab + aRowB + (mi) * 2048 + (ckk)))
#define RDB(ni, ckk) (*(const frag8*)(bb + bRowB + (ni) * 2048 + (ckk)))

#define PHASE(p, SSTAGE, SWAIT) do {                                           \
    if ((p) == 0) {                                                            \
      b00 = RDB(0, ck0); b01 = RDB(0, ck1); b10 = RDB(1, ck0); b11 = RDB(1, ck1); \
      b20 = RDB(2, ck0); b21 = RDB(2, ck1); b30 = RDB(3, ck0); b31 = RDB(3, ck1); \
    }                                                                          \
    frag8 a00 = RDA(2 * (p), ck0), a01 = RDA(2 * (p), ck1);                    \
    frag8 a10 = RDA(2 * (p) + 1, ck0), a11 = RDA(2 * (p) + 1, ck1);            \
    SSTAGE;                                                                    \
    SWAIT;                                                                     \
    __builtin_amdgcn_s_barrier();                                              \
    __builtin_amdgcn_s_setprio(1);                                             \
    acc[2*(p)][0]   = MF(a00, b00, acc[2*(p)][0]);                             \
    acc[2*(p)][1]   = MF(a00, b10, acc[2*(p)][1]);                             \
    acc[2*(p)][2]   = MF(a00, b20, acc[2*(p)][2]);                             \
    acc[2*(p)][3]   = MF(a00, b30, acc[2*(p)][3]);                             \
    acc[2*(p)+1][0] = MF(a10, b00, acc[2*(p)+1][0]);                           \
    acc[2*(p)+1][1] = MF(a10, b10, acc[2*(p)+1][1]);                           \
    acc[2*(p)+1][2] = MF(a10, b20, acc[2*(p)+1][2]);                           \
    acc[2*(p)+1][3] = MF(a10, b30, acc[2*(p)+1][3]);                           \
    acc[2*(p)][0]   = MF(a01, b01, acc[2*(p)][0]);                             \
    acc[2*(p)][1]   = MF(a01, b11, acc[2*(p)][1]);                             \
    acc[2*(p)][2]   = MF(a01, b21, acc[2*(p)][2]);                             \
    acc[2*(p)][3]   = MF(a01, b31, acc[2*(p)][3]);                             \
    acc[2*(p)+1][0] = MF(a11, b01, acc[2*(p)+1][0]);                           \
    acc[2*(p)+1][1] = MF(a11, b11, acc[2*(p)+1][1]);                           \
    acc[2*(p)+1][2] = MF(a11, b21, acc[2*(p)+1][2]);                           \
    acc[2*(p)+1][3] = MF(a11, b31, acc[2*(p)+1][3]);                           \
    __builtin_amdgcn_s_setprio(0);                                             \
    __builtin_amdgcn_s_barrier();                                              \
  } while (0)

#define VM4 asm volatile("s_waitcnt vmcnt(4)" ::: "memory")
#define VM0 asm volatile("s_waitcnt vmcnt(0)" ::: "memory")
#define NOW ((void)0)

#define TILE(t, SA, SB, SWAIT) do {                                            \
    const int _bp2 = ((t) & 1) * 2;                                            \
    char* ab = lds + ((_bp2 + wm) << 14);                                      \
    char* bb = lds + 65536 + ((_bp2 + bhalf) << 14);                           \
    PHASE(0, { if (SA) STAGE(0, 0, (t) + 1, ((t) + 1) & 1); }, NOW);           \
    PHASE(1, { if (SA) STAGE(0, 1, (t) + 1, ((t) + 1) & 1); }, NOW);           \
    PHASE(2, { if (SB) STAGE(1, 0, (t) + 2, (t) & 1); }, NOW);                 \
    PHASE(3, { if (SB) STAGE(1, 1, (t) + 2, (t) & 1); }, SWAIT);               \
  } while (0)

template <typename OutT, int EPI>
__global__ __launch_bounds__(512, 2) void gemm8(const bf16* __restrict__ A,
                                                const bf16* __restrict__ Bt,
                                                OutT* __restrict__ C,
                                                const float* __restrict__ fc,
                                                const float* __restrict__ fs,
                                                float oscale) {
  __shared__ __align__(16) char lds[131072];
  const int K = 4096, N = 4096;
  const int t = threadIdx.x;
  const int lane = t & 63, w = t >> 6;
  const int wm = w >> 2, wn = w & 3;
  const int lr = lane & 15, lg = lane >> 4;
  const int bhalf = wn >> 1;

  const int bid = blockIdx.x;
  const int wg = (bid & 7) * 32 + (bid >> 3);
  const int m0 = (wg >> 4) * 256, n0 = (wg & 15) * 256;

  const bf16* gA[2][2];
  const bf16* gB[2][2];
  int ldsOff0, ldsOff1;
  {
    int c0 = (w * 2 + 0) * 64 + lane;
    int c1 = (w * 2 + 1) * 64 + lane;
    int r0 = c0 >> 3, r1 = c1 >> 3;
    int e0 = ((c0 & 7) ^ (r0 & 7)) * 8;
    int e1 = ((c1 & 7) ^ (r1 & 7)) * 8;
    ldsOff0 = c0 * 16; ldsOff1 = c1 * 16;
    gA[0][0] = A + (size_t)(m0 + r0) * K + e0;
    gA[0][1] = A + (size_t)(m0 + r1) * K + e1;
    gA[1][0] = A + (size_t)(m0 + 128 + r0) * K + e0;
    gA[1][1] = A + (size_t)(m0 + 128 + r1) * K + e1;
    gB[0][0] = Bt + (size_t)(n0 + r0) * K + e0;
    gB[0][1] = Bt + (size_t)(n0 + r1) * K + e1;
    gB[1][0] = Bt + (size_t)(n0 + 128 + r0) * K + e0;
    gB[1][1] = Bt + (size_t)(n0 + 128 + r1) * K + e1;
  }

  const int swz = (lr & 7) << 4;
  const int ck0 = (lg * 16) ^ swz;
  const int ck1 = (64 + lg * 16) ^ swz;
  const int aRowB = lr * 128;
  const int bRowB = ((wn & 1) * 64 + lr) * 128;

  f32x4 acc[8][4];
#pragma unroll
  for (int mi = 0; mi < 8; ++mi)
#pragma unroll
    for (int ni = 0; ni < 4; ++ni) acc[mi][ni] = (f32x4){0.f, 0.f, 0.f, 0.f};

  frag8 b00, b01, b10, b11, b20, b21, b30, b31;

  STAGE(1, 0, 0, 0); STAGE(1, 1, 0, 0);
  STAGE(0, 0, 0, 0); STAGE(0, 1, 0, 0);
  STAGE(1, 0, 1, 1); STAGE(1, 1, 1, 1);
  VM4;
  __builtin_amdgcn_s_barrier();

  for (int tt = 0; tt < 62; tt += 2) {
    TILE(tt, 1, 1, VM4);
    TILE(tt + 1, 1, 1, VM4);
  }
  TILE(62, 1, 0, VM0);
  TILE(63, 0, 0, NOW);

#pragma unroll
  for (int mi = 0; mi < 8; ++mi)
#pragma unroll
    for (int ni = 0; ni < 4; ++ni) {
      f32x4 v = acc[mi][ni];
      int col = n0 + wn * 64 + ni * 16 + lr;
      if (EPI == 1) {
        int i = (col & 127) >> 1;
        const bool odd = (col & 1);
#pragma unroll
        for (int ii = 0; ii < 4; ++ii) {
          int row = m0 + wm * 128 + mi * 16 + lg * 4 + ii;
          int s = row & 1023;
          float c = fc[s * 64 + i], si = fs[s * 64 + i];
          float val = v[ii];
          float par = __shfl_xor(val, 1);
          float o = (val * c + (odd ? par * si : -par * si)) * oscale;
          storeC(C, (size_t)row * N + col, o);
        }
      } else if (EPI == 2) {
        int row0 = m0 + wm * 128 + mi * 16 + lg * 4;
        size_t base = ((size_t)(row0 >> 10) * 4096 + col) * 1024 + (row0 & 1023);
        union { ushort4 s4; unsigned short us[4]; } pk;
#pragma unroll
        for (int ii = 0; ii < 4; ++ii) {
          union { bf16 b; unsigned short u; } cv;
          cv.b = __float2bfloat16(v[ii]);
          pk.us[ii] = cv.u;
        }
        *reinterpret_cast<ushort4*>(reinterpret_cast<bf16*>(C) + base) = pk.s4;
      } else {
#pragma unroll
        for (int ii = 0; ii < 4; ++ii) {
          int row = m0 + wm * 128 + mi * 16 + lg * 4 + ii;
          storeC(C, (size_t)row * N + col, v[ii]);
        }
      }
    }
}

// ---------------- Flash attention v8 (R8-verified, unchanged) ----------------
__global__ __launch_bounds__(512, 4) void attn_kernel(const bf16* __restrict__ q,
                                                      const bf16* __restrict__ k,
                                                      const bf16* __restrict__ vt,
                                                      bf16* __restrict__ out) {
  __shared__ __align__(16) char als[81920];
  const int qt = 7 - blockIdx.x, h = blockIdx.y, b = blockIdx.z;
  const int t = threadIdx.x;
  const int lane = t & 63, w = t >> 6;
  const int lr = lane & 15, lg = lane >> 4;
  const int NT = 2 * qt + 2;

  frag8 aq[4];  // Q pre-scaled by 1/sqrt(128) in the RoPE epilogue
  {
    const bf16* qp = q + ((size_t)(b * 1024 + qt * 128 + w * 16 + lr)) * 4096 + h * 128 + lg * 8;
#pragma unroll
    for (int ks = 0; ks < 4; ++ks) aq[ks] = *reinterpret_cast<const frag8*>(qp + ks * 32);
  }

  const bf16* kbase = k + (size_t)b * 1024 * 4096 + h * 128;
  const bf16* vbase = vt + ((size_t)(b * 32 + h)) * 128 * 1024;

  const int L0 = t * 16, L1 = (t + 512) * 16;
  const int kr0 = L0 >> 8, kr1 = L1 >> 8;
  const size_t kOff0 = (size_t)kr0 * 4096 + (((L0 & 255) ^ ((kr0 & 7) << 4)) >> 1);
  const size_t kOff1 = (size_t)kr1 * 4096 + (((L1 & 255) ^ ((kr1 & 7) << 4)) >> 1);
  const int vr0 = L0 >> 7, vr1 = L1 >> 7;
  const size_t vOff0 = (size_t)vr0 * 1024 + (((L0 & 127) ^ ((vr0 & 7) << 4)) >> 1);
  const size_t vOff1 = (size_t)vr1 * 1024 + (((L1 & 127) ^ ((vr1 & 7) << 4)) >> 1);

#define STAGE_K(tt, bp) do { char* _d = als + (bp) * 16384;                    \
    gl_lds16(kbase + (size_t)(tt) * 262144 + kOff0, _d + L0);                  \
    gl_lds16(kbase + (size_t)(tt) * 262144 + kOff1, _d + L1); } while (0)
#define STAGE_V(tt, bp) do { char* _d = als + 32768 + (bp) * 16384;            \
    gl_lds16(vbase + (size_t)(tt) * 64 + vOff0, _d + L0);                      \
    gl_lds16(vbase + (size_t)(tt) * 64 + vOff1, _d + L1); } while (0)

  f32x4 oacc[8] = {};
  float mrow = -1e30f, lrow = 0.f;
  char* Pw = als + 65536 + w * 2048;
  const int qmaxw = qt * 128 + w * 16 + 15;
  const int qr_g = qt * 128 + w * 16 + lr;

  STAGE_K(0, 0); STAGE_V(0, 0);
  STAGE_K(1, 1); STAGE_V(1, 1);

  for (int kt = 0; kt < NT; ++kt) {
    const int cur = kt & 1;
    const bool act = (kt * 64 <= qmaxw);
    const bool domask = (kt >= 2 * qt);
    char* Kc = als + cur * 16384;
    char* Vc = als + 32768 + cur * 16384;

    if (kt + 1 < NT) { VM4; } else { VM0; }
    __builtin_amdgcn_s_barrier();

    f32x4 sacc[4] = {};
    if (act) {
      __builtin_amdgcn_s_setprio(1);
#pragma unroll
      for (int ks = 0; ks < 4; ++ks) {
#pragma unroll
        for (int ni = 0; ni < 4; ++ni) {
          int n = ni * 16 + lr;
          frag8 bk = *reinterpret_cast<const frag8*>(
              Kc + n * 256 + ((ks * 64 + lg * 16) ^ ((n & 7) << 4)));
          sacc[ni] = MF(bk, aq[ks], sacc[ni]);   // SWAPPED: A=K, B=Q -> S^T
        }
      }
      __builtin_amdgcn_s_setprio(0);
    }
    __builtin_amdgcn_s_barrier();
    if (kt + 2 < NT) STAGE_K(kt + 2, cur);

    if (act) {
      if (domask) {
#pragma unroll
        for (int ni = 0; ni < 4; ++ni)
#pragma unroll
          for (int i = 0; i < 4; ++i) {
            int kc = kt * 64 + ni * 16 + lg * 4 + i;
            if (kc > qr_g) sacc[ni][i] = -1e30f;
          }
      }

      float pm = sacc[0][0];
#pragma unroll
      for (int ni = 0; ni < 4; ++ni)
#pragma unroll
        for (int i = 0; i < 4; ++i) pm = fmaxf(pm, sacc[ni][i]);
      pm = fmaxf(pm, __shfl_xor(pm, 16));
      pm = fmaxf(pm, __shfl_xor(pm, 32));
      const bool skip = __all(pm <= mrow + 8.f);
      float mn, f;
      if (skip) { mn = mrow; f = 1.f; }
      else      { mn = fmaxf(mrow, pm); f = __expf(mrow - mn); mrow = mn; }
      float rs = 0.f;
#pragma unroll
      for (int ni = 0; ni < 4; ++ni)
#pragma unroll
        for (int i = 0; i < 4; ++i) {
          float p = __expf(sacc[ni][i] - mn);
          sacc[ni][i] = p;
          rs += p;
        }
      rs += __shfl_xor(rs, 16);
      rs += __shfl_xor(rs, 32);
      lrow = lrow * f + rs;

#pragma unroll
      for (int ni = 0; ni < 4; ++ni)
#pragma unroll
        for (int jj = 0; jj < 2; ++jj) {
          union { uint32_t u; bf16 hh[2]; } pk;
          pk.hh[0] = __float2bfloat16(sacc[ni][2 * jj]);
          pk.hh[1] = __float2bfloat16(sacc[ni][2 * jj + 1]);
          int kc2 = (ni * 16 + lg * 4 + 2 * jj) * 2;
          *reinterpret_cast<uint32_t*>(Pw + lr * 128 + (kc2 ^ ((lr & 7) << 4))) = pk.u;
        }

      if (!skip) {
        float fi0 = __shfl(f, lg * 4 + 0);
        float fi1 = __shfl(f, lg * 4 + 1);
        float fi2 = __shfl(f, lg * 4 + 2);
        float fi3 = __shfl(f, lg * 4 + 3);
#pragma unroll
        for (int nj = 0; nj < 8; ++nj) {
          oacc[nj][0] *= fi0; oacc[nj][1] *= fi1;
          oacc[nj][2] *= fi2; oacc[nj][3] *= fi3;
        }
      }

      __builtin_amdgcn_s_setprio(1);
#pragma unroll
      for (int ks2 = 0; ks2 < 2; ++ks2) {
        frag8 ap = *reinterpret_cast<const frag8*>(
            Pw + lr * 128 + ((ks2 * 64 + lg * 16) ^ ((lr & 7) << 4)));
#pragma unroll
        for (int nj = 0; nj < 8; ++nj) {
          int d = nj * 16 + lr;
          frag8 bv = *reinterpret_cast<const frag8*>(
              Vc + d * 128 + ((ks2 * 64 + lg * 16) ^ ((d & 7) << 4)));
          oacc[nj] = MF(ap, bv, oacc[nj]);
        }
      }
      __builtin_amdgcn_s_setprio(0);
    }
    __builtin_amdgcn_s_barrier();
    if (kt + 2 < NT) STAGE_V(kt + 2, cur);
  }

  float lv0 = __shfl(lrow, lg * 4 + 0);
  float lv1 = __shfl(lrow, lg * 4 + 1);
  float lv2 = __shfl(lrow, lg * 4 + 2);
  float lv3 = __shfl(lrow, lg * 4 + 3);
#pragma unroll
  for (int nj = 0; nj < 8; ++nj) {
    int srow0 = qt * 128 + w * 16 + lg * 4;
    size_t base = ((size_t)(b * 1024 + srow0)) * 4096 + h * 128 + nj * 16 + lr;
    out[base]          = __float2bfloat16(oacc[nj][0] / lv0);
    out[base + 4096]   = __float2bfloat16(oacc[nj][1] / lv1);
    out[base + 8192]   = __float2bfloat16(oacc[nj][2] / lv2);
    out[base + 12288]  = __float2bfloat16(oacc[nj][3] / lv3);
  }
#undef STAGE_K
#undef STAGE_V
}

// ---------------- host launch ----------------
extern "C" void kernel_launch(void* const* d_in, const int* in_sizes, int n_in,
                              void* d_out, int out_size, void* d_ws, size_t ws_size,
                              hipStream_t stream) {
  const float* x  = (const float*)d_in[0];
  const float* fc = (const float*)d_in[2];
  const float* fs = (const float*)d_in[3];
  const float* wq = (const float*)d_in[5];
  const float* wk = (const float*)d_in[6];
  const float* wv = (const float*)d_in[7];
  const float* wo = (const float*)d_in[8];
  float* out = (float*)d_out;

  const size_t SZ = (size_t)4096 * 4096 * 2;
  char* w = (char*)d_ws;
  bf16* xb  = (bf16*)(w);
  bf16* wbq = (bf16*)(w + SZ);
  bf16* qb  = (bf16*)(w + 2 * SZ);
  bf16* kb  = (bf16*)(w + 3 * SZ);
  bf16* vtb = (bf16*)(w + 4 * SZ);  // V gemm writes transposed layout directly
  bf16* wbk = (bf16*)(w + 5 * SZ);
  bf16* wbv = (bf16*)(w + 6 * SZ);
  bf16* wbo = (bf16*)(w + 7 * SZ);
  bf16* ao  = xb;                    // xb dead after the three QKV GEMMs

  const int n8 = 4096 * 4096 / 8;
  dim3 cgrd(n8 / 256, 5), blk(256);
  dim3 ggrd(256);
  dim3 gblk(512);

  conv_all<<<cgrd, blk, 0, stream>>>(x, wq, wk, wv, wo, xb, wbq, wbk, wbv, wbo);
  gemm8<bf16, 1><<<ggrd, gblk, 0, stream>>>(xb, wbq, qb, fc, fs, 0.08838834764831845f);
  gemm8<bf16, 1><<<ggrd, gblk, 0, stream>>>(xb, wbk, kb, fc, fs, 1.0f);
  gemm8<bf16, 2><<<ggrd, gblk, 0, stream>>>(xb, wbv, vtb, fc, fs, 1.0f);
  attn_kernel<<<dim3(8, 32, 4), gblk, 0, stream>>>(qb, kb, vtb, ao);
  gemm8<float, 0><<<ggrd, gblk, 0, stream>>>(ao, wbo, out, fc, fs, 1.0f);
}